// Round 8
// baseline (310.475 us; speedup 1.0000x reference)
//
#include <hip/hip_runtime.h>
#include <stdint.h>

typedef __bf16 bf16;
typedef __bf16 bf16x8 __attribute__((ext_vector_type(8)));  // 16B
typedef __bf16 bf16x4 __attribute__((ext_vector_type(4)));  // 8B
typedef float  f32x4  __attribute__((ext_vector_type(4)));

#define MFMA_BF16(a, b, c) __builtin_amdgcn_mfma_f32_16x16x32_bf16((a), (b), (c), 0, 0, 0)

static constexpr int BATCH = 2;
static constexpr int SEQ   = 2048;
static constexpr int DIM   = 1024;
static constexpr int HDIM  = 64;
static constexpr int MROWS = BATCH * SEQ;   // 4096
static constexpr int NIN   = 11;

// element offsets of each converted input inside the conv region (dict order)
static const long long H_OFF[NIN] = {
    0, 4194304, 8388608,                 // q, k, v
    12582912, 13631488,                  // Wq, bq
    13632512, 14681088,                  // Wk, bk
    14682112, 15730688,                  // Wv, bv
    15731712, 16780288                   // Wo, bo
};
static constexpr long long CONV_TOTAL = 16781312;

struct InPack { const void* p[NIN]; long long o[NIN]; int n[NIN]; };

__device__ __forceinline__ float scrubf(float v) {
    unsigned b = __float_as_uint(v);
    return ((b & 0x7f800000u) == 0x7f800000u) ? 0.f : v;  // NaN/Inf -> 0
}

typedef const __attribute__((address_space(1))) void* gvp;
typedef __attribute__((address_space(3))) void* svp;
__device__ __forceinline__ void glds16(const bf16* g, bf16* l) {
    __builtin_amdgcn_global_load_lds((gvp)(const void*)g, (svp)(void*)l, 16, 0, 0);
}

// ---------------------------------------------------------------------------
// dtype detection (fp32 vs bf16) per input buffer. flags[i]=1 -> fp32.
// ---------------------------------------------------------------------------
__global__ void detect_kernel(InPack in, int* __restrict__ flags) {
    const int i = blockIdx.x;
    const unsigned short* s = (const unsigned short*)in.p[i];
    const int scan = in.n[i] < 65536 ? in.n[i] : 65536;
    __shared__ int bad;
    if (threadIdx.x == 0) bad = 0;
    __syncthreads();
    int local = 0;
    for (int j = threadIdx.x; j < scan; j += 256) {
        const int e = (s[j] >> 7) & 0xFF;
        if (e >= 0x89) ++local;   // |x|>=1024 / inf / nan: impossible for true bf16 here
    }
    if (local) atomicAdd(&bad, local);
    __syncthreads();
    if (threadIdx.x == 0) flags[i] = (bad > 0) ? 1 : 0;
}

// ---------------------------------------------------------------------------
// Convert every input to clean bf16 in the conv region (x4 vectorized).
// ---------------------------------------------------------------------------
__global__ void convert_kernel(InPack in, bf16* __restrict__ dstbase,
                               const int* __restrict__ flags) {
    const int i = blockIdx.y;
    const int n4 = in.n[i] >> 2;
    bf16* dst = dstbase + in.o[i];
    const bool isf32 = (flags[i] != 0);
    for (int j = blockIdx.x * 256 + threadIdx.x; j < n4; j += gridDim.x * 256) {
        float v0, v1, v2, v3;
        if (isf32) {
            const float4 f = ((const float4*)in.p[i])[j];
            v0 = f.x; v1 = f.y; v2 = f.z; v3 = f.w;
        } else {
            const ushort4 u = ((const ushort4*)in.p[i])[j];
            v0 = __uint_as_float((unsigned)u.x << 16);
            v1 = __uint_as_float((unsigned)u.y << 16);
            v2 = __uint_as_float((unsigned)u.z << 16);
            v3 = __uint_as_float((unsigned)u.w << 16);
        }
        bf16x4 o = {(bf16)scrubf(v0), (bf16)scrubf(v1), (bf16)scrubf(v2), (bf16)scrubf(v3)};
        *(bf16x4*)&dst[(size_t)j * 4] = o;
    }
}

// ---------------------------------------------------------------------------
// BK=64 bf16 GEMM core. 128x128 tile, 16 k-iters, all staging via glds16 with
// XOR-chunk source swizzle: phys chunk p of row r holds logical chunk p^(r&7)
// (chunk = 8 elems/16B). Staging dest = wave base + lane*16 (rigid) -> lane l
// stages row base+(l>>3), phys chunk l&7, i.e. source col ((l&7)^(l>>3))*8.
// Frag reads: logical chunk kc*4+quad -> phys (kc*4+quad)^(ln&7): 8 start-bank
// positions, same spread as the m97-validated layout.
// ---------------------------------------------------------------------------
// QKV GEMM: z selects (A,W,bias,C); z==2 (V) stores C transposed per head:
// Vt_g[((b*16+h)*64+e)*SEQ + s], vectorized bf16x4 along s.
__global__ __launch_bounds__(256, 2) void gemm_qkv_kernel(
    const bf16* __restrict__ A0, const bf16* __restrict__ W0,
    const bf16* __restrict__ b0, bf16* __restrict__ C0,
    const bf16* __restrict__ A1, const bf16* __restrict__ W1,
    const bf16* __restrict__ b1, bf16* __restrict__ C1,
    const bf16* __restrict__ A2, const bf16* __restrict__ W2,
    const bf16* __restrict__ b2, bf16* __restrict__ Vtg)
{
    const int z = blockIdx.z;
    const bf16* A    = (z == 0) ? A0 : (z == 1) ? A1 : A2;
    const bf16* W    = (z == 0) ? W0 : (z == 1) ? W1 : W2;
    const bf16* bias = (z == 0) ? b0 : (z == 1) ? b1 : b2;

    const int n0 = blockIdx.x * 128;
    const int m0 = blockIdx.y * 128;

    __shared__ bf16 As[128 * 64];
    __shared__ bf16 Bs[128 * 64];

    const int t    = threadIdx.x;
    const int w    = t >> 6;
    const int lane = t & 63;
    const int ln   = t & 15;
    const int quad = (t >> 4) & 3;
    const int wm   = (w & 1) * 64;
    const int wn   = (w >> 1) * 64;

    const int srow8 = lane >> 3;                  // 0..7: row within 8-row group
    const int scol  = ((lane & 7) ^ srow8) * 8;   // swizzled source column
    const bf16* gA = A + (size_t)(m0 + w * 32 + srow8) * DIM + scol;
    const bf16* gW = W + (size_t)(n0 + w * 32 + srow8) * DIM + scol;
    bf16* lA = &As[(w * 32) * 64];
    bf16* lB = &Bs[(w * 32) * 64];

    f32x4 acc[4][4];
#pragma unroll
    for (int i = 0; i < 4; ++i)
#pragma unroll
        for (int j = 0; j < 4; ++j) acc[i][j] = (f32x4){0.f, 0.f, 0.f, 0.f};

    for (int k0 = 0; k0 < DIM; k0 += 64) {
        __syncthreads();
#pragma unroll
        for (int i = 0; i < 4; ++i) {
            glds16(gA + (size_t)(i * 8) * DIM + k0, lA + i * 8 * 64);
            glds16(gW + (size_t)(i * 8) * DIM + k0, lB + i * 8 * 64);
        }
        __syncthreads();

#pragma unroll
        for (int kc = 0; kc < 2; ++kc) {
            const int ch = ((kc * 4 + quad) ^ (ln & 7)) << 3;
            bf16x8 af[4], wf[4];
#pragma unroll
            for (int mt = 0; mt < 4; ++mt)
                af[mt] = *(const bf16x8*)&As[(wm + mt * 16 + ln) * 64 + ch];
#pragma unroll
            for (int nt = 0; nt < 4; ++nt)
                wf[nt] = *(const bf16x8*)&Bs[(wn + nt * 16 + ln) * 64 + ch];
#pragma unroll
            for (int mt = 0; mt < 4; ++mt)
#pragma unroll
                for (int nt = 0; nt < 4; ++nt)
                    acc[mt][nt] = MFMA_BF16(af[mt], wf[nt], acc[mt][nt]);
        }
    }

    if (z == 2) {
        // V epilogue: store transposed per head
#pragma unroll
        for (int nt = 0; nt < 4; ++nt) {
            const int col = n0 + wn + nt * 16 + ln;       // d
            const int h2 = col >> 6, e = col & 63;
            const float bv = (float)bias[col];
#pragma unroll
            for (int mt = 0; mt < 4; ++mt) {
                const int row = m0 + wm + mt * 16 + quad * 4;
                const int bb = row >> 11, s = row & 2047;
                bf16x4 o = {(bf16)(acc[mt][nt][0] + bv), (bf16)(acc[mt][nt][1] + bv),
                            (bf16)(acc[mt][nt][2] + bv), (bf16)(acc[mt][nt][3] + bv)};
                *(bf16x4*)&Vtg[((size_t)((bb * 16 + h2) * 64 + e)) * SEQ + s] = o;
            }
        }
    } else {
        bf16* C = (z == 0) ? C0 : C1;
#pragma unroll
        for (int nt = 0; nt < 4; ++nt) {
            const int col = n0 + wn + nt * 16 + ln;
            const float bv = (float)bias[col];
#pragma unroll
            for (int mt = 0; mt < 4; ++mt)
#pragma unroll
                for (int r = 0; r < 4; ++r) {
                    const int row = m0 + wm + mt * 16 + quad * 4 + r;
                    C[(size_t)row * DIM + col] = (bf16)(acc[mt][nt][r] + bv);
                }
        }
    }
}

// Output GEMM: C = A @ Wo^T + bo, A/W/bias bf16, C dtype per flags[0].
__global__ __launch_bounds__(256, 2) void gemm_out_kernel(
    const bf16* __restrict__ A, const bf16* __restrict__ W,
    const bf16* __restrict__ bias, void* __restrict__ C,
    const int* __restrict__ flags)
{
    const bool of32 = flags[0] != 0;
    const int n0 = blockIdx.x * 128;
    const int m0 = blockIdx.y * 128;

    __shared__ bf16 As[128 * 64];
    __shared__ bf16 Bs[128 * 64];

    const int t    = threadIdx.x;
    const int w    = t >> 6;
    const int lane = t & 63;
    const int ln   = t & 15;
    const int quad = (t >> 4) & 3;
    const int wm   = (w & 1) * 64;
    const int wn   = (w >> 1) * 64;

    const int srow8 = lane >> 3;
    const int scol  = ((lane & 7) ^ srow8) * 8;
    const bf16* gA = A + (size_t)(m0 + w * 32 + srow8) * DIM + scol;
    const bf16* gW = W + (size_t)(n0 + w * 32 + srow8) * DIM + scol;
    bf16* lA = &As[(w * 32) * 64];
    bf16* lB = &Bs[(w * 32) * 64];

    f32x4 acc[4][4];
#pragma unroll
    for (int i = 0; i < 4; ++i)
#pragma unroll
        for (int j = 0; j < 4; ++j) acc[i][j] = (f32x4){0.f, 0.f, 0.f, 0.f};

    for (int k0 = 0; k0 < DIM; k0 += 64) {
        __syncthreads();
#pragma unroll
        for (int i = 0; i < 4; ++i) {
            glds16(gA + (size_t)(i * 8) * DIM + k0, lA + i * 8 * 64);
            glds16(gW + (size_t)(i * 8) * DIM + k0, lB + i * 8 * 64);
        }
        __syncthreads();

#pragma unroll
        for (int kc = 0; kc < 2; ++kc) {
            const int ch = ((kc * 4 + quad) ^ (ln & 7)) << 3;
            bf16x8 af[4], wf[4];
#pragma unroll
            for (int mt = 0; mt < 4; ++mt)
                af[mt] = *(const bf16x8*)&As[(wm + mt * 16 + ln) * 64 + ch];
#pragma unroll
            for (int nt = 0; nt < 4; ++nt)
                wf[nt] = *(const bf16x8*)&Bs[(wn + nt * 16 + ln) * 64 + ch];
#pragma unroll
            for (int mt = 0; mt < 4; ++mt)
#pragma unroll
                for (int nt = 0; nt < 4; ++nt)
                    acc[mt][nt] = MFMA_BF16(af[mt], wf[nt], acc[mt][nt]);
        }
    }

#pragma unroll
    for (int nt = 0; nt < 4; ++nt) {
        const int col = n0 + wn + nt * 16 + ln;
        const float bv = (float)bias[col];
#pragma unroll
        for (int mt = 0; mt < 4; ++mt)
#pragma unroll
            for (int r = 0; r < 4; ++r) {
                const int row = m0 + wm + mt * 16 + quad * 4 + r;
                if (of32) ((float*)C)[(size_t)row * DIM + col] = acc[mt][nt][r] + bv;
                else      ((bf16*)C)[(size_t)row * DIM + col] = (bf16)(acc[mt][nt][r] + bv);
            }
    }
}

// ---------------------------------------------------------------------------
// Flash attention (unchanged from R7): S^T formulation, BQ=128, async glds16
// staging with source-side XOR-chunk swizzles, V pre-transposed (Vtg).
// ---------------------------------------------------------------------------
__global__ __launch_bounds__(256, 2) void attn_kernel(
    const bf16* __restrict__ Q, const bf16* __restrict__ K,
    const bf16* __restrict__ Vtg, bf16* __restrict__ O)
{
    const int qt = blockIdx.x;        // 0..15: 128 q-rows
    const int bh = blockIdx.y;        // 0..31
    const int b  = bh >> 4;
    const int h  = bh & 15;

    __shared__ bf16 Ks[128 * 64];     // swizzled, stride 64
    __shared__ bf16 Vt[64 * 128];     // swizzled, stride 128
    __shared__ bf16 Ps[64 * 136];     // padded 136

    const int t    = threadIdx.x;
    const int w    = t >> 6;
    const int lane = t & 63;
    const int ln   = lane & 15;
    const int quad = lane >> 4;

    const int q0 = qt * 128;

    const float sc = 0.125f * 1.44269504089f;   // 1/sqrt(HD) * log2(e)
    bf16x8 qf[2][2];
#pragma unroll
    for (int g = 0; g < 2; ++g) {
        const bf16* qrow = Q + (size_t)(b * SEQ + q0 + w * 32 + g * 16 + ln) * DIM + h * HDIM;
        qf[g][0] = *(const bf16x8*)(qrow + quad * 8);
        qf[g][1] = *(const bf16x8*)(qrow + 32 + quad * 8);
#pragma unroll
        for (int i = 0; i < 8; ++i) {
            qf[g][0][i] = (bf16)((float)qf[g][0][i] * sc);
            qf[g][1][i] = (bf16)((float)qf[g][1][i] * sc);
        }
    }

    f32x4 o_acc[2][4];
#pragma unroll
    for (int g = 0; g < 2; ++g)
#pragma unroll
        for (int c = 0; c < 4; ++c) o_acc[g][c] = (f32x4){0.f, 0.f, 0.f, 0.f};
    float m_s[2] = {-1e30f, -1e30f};
    float l_s[2] = {0.f, 0.f};

    const int kr_off = lane >> 3;
    const int k_lc   = (lane & 7) ^ kr_off;
    const int ve_off = lane >> 4;
    const int v_pc   = lane & 15;
    const size_t vrowbase = (size_t)((b * 16 + h) * 64);

    const int psrow = (w * 16 + ln) * 136;

    for (int kb = 0; kb < SEQ; kb += 128) {
        __syncthreads();
#pragma unroll
        for (int i = 0; i < 4; ++i) {
            const int r = w * 32 + i * 8 + kr_off;
            glds16(K + (size_t)(b * SEQ + kb + r) * DIM + h * HDIM + k_lc * 8,
                   &Ks[(w * 32 + i * 8) * 64]);
        }
#pragma unroll
        for (int i = 0; i < 4; ++i) {
            const int e  = w * 16 + i * 4 + ve_off;
            const int lc = v_pc ^ (i * 4 + ve_off);
            glds16(Vtg + (vrowbase + e) * SEQ + kb + lc * 8,
                   &Vt[(w * 16 + i * 4) * 128]);
        }
        __syncthreads();

        f32x4 sa0[8], sa1[8];
#pragma unroll
        for (int nt = 0; nt < 8; ++nt) {
            const int rr = (nt * 16 + ln) * 64;
            const bf16x8 kf0 = *(const bf16x8*)&Ks[rr + ((quad ^ (ln & 7)) << 3)];
            const bf16x8 kf1 = *(const bf16x8*)&Ks[rr + (((quad + 4) ^ (ln & 7)) << 3)];
            f32x4 z0 = (f32x4){0.f, 0.f, 0.f, 0.f};
            z0 = MFMA_BF16(kf0, qf[0][0], z0);
            z0 = MFMA_BF16(kf1, qf[0][1], z0);
            sa0[nt] = z0;
            f32x4 z1 = (f32x4){0.f, 0.f, 0.f, 0.f};
            z1 = MFMA_BF16(kf0, qf[1][0], z1);
            z1 = MFMA_BF16(kf1, qf[1][1], z1);
            sa1[nt] = z1;
        }

        float al[2];
#pragma unroll
        for (int g = 0; g < 2; ++g) {
            f32x4* sa = g ? sa1 : sa0;
            float mx = -1e30f;
#pragma unroll
            for (int nt = 0; nt < 8; ++nt)
#pragma unroll
                for (int r = 0; r < 4; ++r) mx = fmaxf(mx, sa[nt][r]);
            mx = fmaxf(mx, __shfl_xor(mx, 16));
            mx = fmaxf(mx, __shfl_xor(mx, 32));
            const float mn = fmaxf(m_s[g], mx);
            al[g] = exp2f(m_s[g] - mn);
            m_s[g] = mn;
            float rs = 0.f;
#pragma unroll
            for (int nt = 0; nt < 8; ++nt)
#pragma unroll
                for (int r = 0; r < 4; ++r) {
                    const float p = exp2f(sa[nt][r] - mn);
                    sa[nt][r] = p;
                    rs += p;
                }
            rs += __shfl_xor(rs, 16);
            rs += __shfl_xor(rs, 32);
            l_s[g] = l_s[g] * al[g] + rs;
#pragma unroll
            for (int r = 0; r < 4; ++r) {
                const float alr = __shfl(al[g], quad * 4 + r);
#pragma unroll
                for (int c = 0; c < 4; ++c) o_acc[g][c][r] *= alr;
            }
        }

#pragma unroll
        for (int nt = 0; nt < 8; ++nt) {
            bf16x4 pk = {(bf16)sa0[nt][0], (bf16)sa0[nt][1],
                         (bf16)sa0[nt][2], (bf16)sa0[nt][3]};
            *(bf16x4*)&Ps[psrow + nt * 16 + quad * 4] = pk;
        }
        __asm__ volatile("s_waitcnt lgkmcnt(0)" ::: "memory");
        bf16x8 pf0[4];
#pragma unroll
        for (int kc = 0; kc < 4; ++kc)
            pf0[kc] = *(const bf16x8*)&Ps[psrow + kc * 32 + quad * 8];
        __asm__ volatile("s_waitcnt lgkmcnt(0)" ::: "memory");
#pragma unroll
        for (int nt = 0; nt < 8; ++nt) {
            bf16x4 pk = {(bf16)sa1[nt][0], (bf16)sa1[nt][1],
                         (bf16)sa1[nt][2], (bf16)sa1[nt][3]};
            *(bf16x4*)&Ps[psrow + nt * 16 + quad * 4] = pk;
        }
        bf16x8 vf[4][4];
#pragma unroll
        for (int kc = 0; kc < 4; ++kc)
#pragma unroll
            for (int c = 0; c < 4; ++c) {
                const int e = c * 16 + ln;
                const int pc = (kc * 4 + quad) ^ ln;
                vf[kc][c] = *(const bf16x8*)&Vt[e * 128 + pc * 8];
            }
        __asm__ volatile("s_waitcnt lgkmcnt(0)" ::: "memory");

#pragma unroll
        for (int kc = 0; kc < 4; ++kc)
#pragma unroll
            for (int c = 0; c < 4; ++c)
                o_acc[0][c] = MFMA_BF16(pf0[kc], vf[kc][c], o_acc[0][c]);
        bf16x8 pf1[4];
#pragma unroll
        for (int kc = 0; kc < 4; ++kc)
            pf1[kc] = *(const bf16x8*)&Ps[psrow + kc * 32 + quad * 8];
        __asm__ volatile("s_waitcnt lgkmcnt(0)" ::: "memory");
#pragma unroll
        for (int kc = 0; kc < 4; ++kc)
#pragma unroll
            for (int c = 0; c < 4; ++c)
                o_acc[1][c] = MFMA_BF16(pf1[kc], vf[kc][c], o_acc[1][c]);
    }

#pragma unroll
    for (int g = 0; g < 2; ++g) {
        const float linv = 1.0f / l_s[g];
#pragma unroll
        for (int r = 0; r < 4; ++r) {
            const float lr = __shfl(linv, quad * 4 + r);
            const size_t rowoff =
                (size_t)(b * SEQ + q0 + w * 32 + g * 16 + quad * 4 + r) * DIM + h * HDIM;
#pragma unroll
            for (int c = 0; c < 4; ++c)
                O[rowoff + c * 16 + ln] = (bf16)(o_acc[g][c][r] * lr);
        }
    }
}

extern "C" void kernel_launch(void* const* d_in, const int* in_sizes, int n_in,
                              void* d_out, int out_size, void* d_ws, size_t ws_size,
                              hipStream_t stream) {
    // ws: Qb, Kb, Vtg, Ob (bf16, 8 MB each) + conv (33.6 MB) + flags
    bf16* Qb   = (bf16*)d_ws;
    bf16* Kb   = Qb + (size_t)MROWS * DIM;
    bf16* Vtg  = Kb + (size_t)MROWS * DIM;
    bf16* Ob   = Vtg + (size_t)MROWS * DIM;
    bf16* conv = Ob + (size_t)MROWS * DIM;
    int*  flags = (int*)(conv + CONV_TOTAL);

    InPack pack;
    for (int i = 0; i < NIN; ++i) {
        pack.p[i] = d_in[i];
        pack.o[i] = H_OFF[i];
        pack.n[i] = in_sizes[i];
    }

    detect_kernel<<<NIN, 256, 0, stream>>>(pack, flags);
    convert_kernel<<<dim3(512, NIN), 256, 0, stream>>>(pack, conv, flags);

    const bf16* qc  = conv + H_OFF[0];
    const bf16* kc  = conv + H_OFF[1];
    const bf16* vc  = conv + H_OFF[2];
    const bf16* Wqc = conv + H_OFF[3];
    const bf16* bqc = conv + H_OFF[4];
    const bf16* Wkc = conv + H_OFF[5];
    const bf16* bkc = conv + H_OFF[6];
    const bf16* Wvc = conv + H_OFF[7];
    const bf16* bvc = conv + H_OFF[8];
    const bf16* Woc = conv + H_OFF[9];
    const bf16* boc = conv + H_OFF[10];

    gemm_qkv_kernel<<<dim3(DIM / 128, MROWS / 128, 3), 256, 0, stream>>>(
        qc, Wqc, bqc, Qb,
        kc, Wkc, bkc, Kb,
        vc, Wvc, bvc, Vtg);

    attn_kernel<<<dim3(SEQ / 128, BATCH * 16), 256, 0, stream>>>(Qb, Kb, Vtg, Ob);

    gemm_out_kernel<<<dim3(DIM / 128, MROWS / 128), 256, 0, stream>>>(
        Ob, Woc, boc, d_out, flags);
}